// Round 12
// baseline (99.048 us; speedup 1.0000x reference)
//
#include <hip/hip_runtime.h>

#define B_ 2048
#define S_ 256
#define V_ 30522
#define D_ 768
#define C_ 100
#define NPAD 112  // C_ padded to 7x16 for MFMA col tiles

// ---- bf16 helpers ---------------------------------------------------------
__device__ __forceinline__ unsigned short f2bf(float x) {
  unsigned u = __builtin_bit_cast(unsigned, x);
  u = (u + 0x7fffu + ((u >> 16) & 1u)) >> 16;
  return (unsigned short)u;
}

typedef __attribute__((ext_vector_type(8))) short bf16x8;
typedef __attribute__((ext_vector_type(4))) float f32x4;

// ---------------------------------------------------------------------------
// Fused prep: [0,512) compact ids; [512,1088) W1 transpose+bf16;
// [1088,1184) W2 transpose+pad+bf16.
// ---------------------------------------------------------------------------
__global__ __launch_bounds__(256) void prep_kernel(
    const int* __restrict__ ids, const int* __restrict__ mask,
    const float* __restrict__ w1, const float* __restrict__ w2,
    int* __restrict__ cids, int* __restrict__ cnts,
    unsigned short* __restrict__ w1t, unsigned short* __restrict__ w2t) {
  const int bid = blockIdx.x;
  const int t = threadIdx.x;
  if (bid < 512) {
    const int wv = t >> 6, lane = t & 63;
    const int b = bid * 4 + wv;
    const int base = b * S_;
    int total = 0;
#pragma unroll
    for (int r = 0; r < S_ / 64; ++r) {
      const int s = r * 64 + lane;
      const int m = mask[base + s];
      const unsigned long long bal = __ballot(m != 0);
      const int pre = __popcll(bal & ((1ull << lane) - 1ull));
      if (m) cids[base + total + pre] = ids[base + s];
      total += __popcll(bal);
    }
    if (lane == 0) cnts[b] = total;
  } else if (bid < 1088) {
    __shared__ float tile[32][33];
    const int local = bid - 512;
    const int k0 = (local % 24) * 32, n0 = (local / 24) * 32;
    const int tx = t & 31, ty = t >> 5;
#pragma unroll
    for (int i = 0; i < 4; ++i)
      tile[ty + i * 8][tx] = w1[(size_t)(k0 + ty + i * 8) * D_ + n0 + tx];
    __syncthreads();
#pragma unroll
    for (int i = 0; i < 4; ++i) {
      const int n = ty + i * 8;
      w1t[(size_t)(n0 + n) * D_ + k0 + tx] = f2bf(tile[tx][n]);
    }
  } else {
    __shared__ float tile[32][33];
    const int local = bid - 1088;
    const int k0 = (local % 24) * 32, n0 = (local / 24) * 32;
    const int tx = t & 31, ty = t >> 5;
#pragma unroll
    for (int i = 0; i < 4; ++i) {
      const int k = k0 + ty + i * 8, n = n0 + tx;
      tile[ty + i * 8][tx] = (n < C_) ? w2[(size_t)k * C_ + n] : 0.f;
    }
    __syncthreads();
#pragma unroll
    for (int i = 0; i < 4; ++i) {
      const int n = n0 + ty + i * 8;
      if (n < NPAD)
        w2t[(size_t)n * D_ + k0 + tx] = f2bf(tile[tx][ty + i * 8]);
    }
  }
}

// ---------------------------------------------------------------------------
// Pool v8 (R8 structure + unpredicated inner loop): XCD-pinned column-sliced
// gather, ONE pass per launch (3 serialized launches -> no phase drift).
// Per pass: 2048 blocks; chunk = pass*8 + (bid&7); slice = 30522x128B =
// 3.9 MB, L2-resident. grp = bid>>3; wave wv pools 2 samples; lane = 8
// token-slots x 8 col-groups; 8 float4 in flight. sids padded to 256 with
// id0; over-count fixed by one subtract after the reduce.
// ---------------------------------------------------------------------------
__global__ __launch_bounds__(256) void pool_sliced(
    const int* __restrict__ cids, const int* __restrict__ cnts,
    const float* __restrict__ table, unsigned short* __restrict__ bowb,
    int pass) {
  __shared__ int sids[4][S_];
  const int bid = blockIdx.x;
  const int chunk = pass * 8 + (bid & 7);
  const int grp = bid >> 3;        // 0..255
  const int wv = threadIdx.x >> 6;
  const int lane = threadIdx.x & 63;
  const int sub = lane >> 3;       // token slot 0..7
  const int cg = lane & 7;         // col group (4 f32)
  const int coff = chunk * 32 + cg * 4;

  for (int i = 0; i < 2; ++i) {
    const int smp = grp * 8 + wv * 2 + i;
    const int cnt = cnts[smp];
    const int* cp = cids + (size_t)smp * S_;
    const int id0 = cp[0];
    // stage ids to LDS, padded to 256 with id0 (same-wave write->read)
#pragma unroll
    for (int r = 0; r < S_ / 64; ++r) {
      const int idx = r * 64 + lane;
      sids[wv][idx] = (idx < cnt) ? cp[idx] : id0;
    }
    float a0 = 0.f, a1 = 0.f, a2 = 0.f, a3 = 0.f;
    const int nb = (cnt + 63) >> 6;  // 64-token batches (<=4)
    for (int b = 0; b < nb; ++b) {
      float4 v[8];
#pragma unroll
      for (int j = 0; j < 8; ++j) {
        const int id = sids[wv][b * 64 + j * 8 + sub];
        v[j] = *reinterpret_cast<const float4*>(table + (size_t)id * D_ + coff);
      }
#pragma unroll
      for (int j = 0; j < 8; ++j) {
        a0 += v[j].x; a1 += v[j].y; a2 += v[j].z; a3 += v[j].w;
      }
    }
    // reduce over token slots (lane bits 3,4,5)
#pragma unroll
    for (int m = 8; m <= 32; m <<= 1) {
      a0 += __shfl_xor(a0, m);
      a1 += __shfl_xor(a1, m);
      a2 += __shfl_xor(a2, m);
      a3 += __shfl_xor(a3, m);
    }
    if (sub == 0) {
      // remove the pad contributions (pads copies of row id0)
      const float fp = (float)(nb * 64 - cnt);
      const float4 v0 =
          *reinterpret_cast<const float4*>(table + (size_t)id0 * D_ + coff);
      a0 -= fp * v0.x; a1 -= fp * v0.y; a2 -= fp * v0.z; a3 -= fp * v0.w;
      const float inv = 1.0f / (float)cnt;
      ushort4 o;
      o.x = f2bf(a0 * inv); o.y = f2bf(a1 * inv);
      o.z = f2bf(a2 * inv); o.w = f2bf(a3 * inv);
      *reinterpret_cast<ushort4*>(bowb + (size_t)smp * D_ + coff) = o;
    }
  }
}

// ---------------------------------------------------------------------------
// GEMM1 (MFMA bf16): Hb = relu(bow @ W1 + b1), bf16 out. BM=32 BN=64 BK=64.
// ---------------------------------------------------------------------------
#define G1_BM 32
#define G1_BN 64
#define G1_LDK 72  // 64 + 8 pad (ushorts) -> 144B row stride (16B aligned)

__global__ __launch_bounds__(256) void gemm1_mfma(
    const unsigned short* __restrict__ Ab, const unsigned short* __restrict__ Bt,
    const float* __restrict__ bias, unsigned short* __restrict__ Hb) {
  __shared__ unsigned short As[G1_BM][G1_LDK];
  __shared__ unsigned short Bs[G1_BN][G1_LDK];
  const int tid = threadIdx.x;
  const int bm = blockIdx.x * G1_BM;
  const int bn = blockIdx.y * G1_BN;
  const int w = tid >> 6;
  const int l = tid & 63;
  const int r = l & 15;
  const int g = l >> 4;

  f32x4 acc0 = {0.f, 0.f, 0.f, 0.f};
  f32x4 acc1 = {0.f, 0.f, 0.f, 0.f};

  const int ar = tid >> 3;          // 0..31
  const int kc8 = (tid & 7) * 8;    // 0,8,...,56

  for (int k0 = 0; k0 < D_; k0 += 64) {
    __syncthreads();
    *reinterpret_cast<int4*>(&As[ar][kc8]) =
        *reinterpret_cast<const int4*>(&Ab[(size_t)(bm + ar) * D_ + k0 + kc8]);
    *reinterpret_cast<int4*>(&Bs[ar][kc8]) =
        *reinterpret_cast<const int4*>(&Bt[(size_t)(bn + ar) * D_ + k0 + kc8]);
    *reinterpret_cast<int4*>(&Bs[ar + 32][kc8]) =
        *reinterpret_cast<const int4*>(&Bt[(size_t)(bn + ar + 32) * D_ + k0 + kc8]);
    __syncthreads();
    const bf16x8 a00 = *reinterpret_cast<const bf16x8*>(&As[r][g * 8]);
    const bf16x8 a01 = *reinterpret_cast<const bf16x8*>(&As[r][32 + g * 8]);
    const bf16x8 a10 = *reinterpret_cast<const bf16x8*>(&As[16 + r][g * 8]);
    const bf16x8 a11 = *reinterpret_cast<const bf16x8*>(&As[16 + r][32 + g * 8]);
    const bf16x8 b0 = *reinterpret_cast<const bf16x8*>(&Bs[w * 16 + r][g * 8]);
    const bf16x8 b1 = *reinterpret_cast<const bf16x8*>(&Bs[w * 16 + r][32 + g * 8]);
    acc0 = __builtin_amdgcn_mfma_f32_16x16x32_bf16(a00, b0, acc0, 0, 0, 0);
    acc0 = __builtin_amdgcn_mfma_f32_16x16x32_bf16(a01, b1, acc0, 0, 0, 0);
    acc1 = __builtin_amdgcn_mfma_f32_16x16x32_bf16(a10, b0, acc1, 0, 0, 0);
    acc1 = __builtin_amdgcn_mfma_f32_16x16x32_bf16(a11, b1, acc1, 0, 0, 0);
  }

  const int col = bn + w * 16 + r;
  const float bb = bias[col];
#pragma unroll
  for (int q = 0; q < 4; ++q) {
    const int row0 = bm + g * 4 + q;
    float v0 = acc0[q] + bb;
    v0 = v0 > 0.f ? v0 : 0.f;
    Hb[(size_t)row0 * D_ + col] = f2bf(v0);
    float v1 = acc1[q] + bb;
    v1 = v1 > 0.f ? v1 : 0.f;
    Hb[(size_t)(row0 + 16) * D_ + col] = f2bf(v1);
  }
}

// ---------------------------------------------------------------------------
// GEMM2 (MFMA bf16): scores = Hb @ W2 + b2, written twice (tuple return).
// ---------------------------------------------------------------------------
__global__ __launch_bounds__(64) void gemm2_mfma(
    const unsigned short* __restrict__ Hb, const unsigned short* __restrict__ w2t,
    const float* __restrict__ b2, float* __restrict__ out) {
  const int bm = blockIdx.x * 16;
  const int bn = blockIdx.y * 16;
  const int l = threadIdx.x;
  const int r = l & 15;
  const int g = l >> 4;

  const unsigned short* ap = Hb + (size_t)(bm + r) * D_ + g * 8;
  const unsigned short* bp = w2t + (size_t)(bn + r) * D_ + g * 8;

  f32x4 acc = {0.f, 0.f, 0.f, 0.f};
#pragma unroll
  for (int k0 = 0; k0 < D_; k0 += 32) {
    const bf16x8 av = *reinterpret_cast<const bf16x8*>(ap + k0);
    const bf16x8 bv = *reinterpret_cast<const bf16x8*>(bp + k0);
    acc = __builtin_amdgcn_mfma_f32_16x16x32_bf16(av, bv, acc, 0, 0, 0);
  }

  const int col = bn + r;
  if (col < C_) {
    const float bb = b2[col];
#pragma unroll
    for (int q = 0; q < 4; ++q) {
      const int row = bm + g * 4 + q;
      const float v = acc[q] + bb;
      out[(size_t)row * C_ + col] = v;
      out[(size_t)row * C_ + col + (size_t)B_ * C_] = v;
    }
  }
}

// ---------------------------------------------------------------------------
extern "C" void kernel_launch(void* const* d_in, const int* in_sizes, int n_in,
                              void* d_out, int out_size, void* d_ws,
                              size_t ws_size, hipStream_t stream) {
  const int* ids = (const int*)d_in[0];
  const int* mask = (const int*)d_in[1];
  const float* table = (const float*)d_in[2];
  const float* W1 = (const float*)d_in[3];
  const float* b1 = (const float*)d_in[4];
  const float* W2 = (const float*)d_in[5];
  const float* b2 = (const float*)d_in[6];
  float* out = (float*)d_out;

  const size_t BOWB = (size_t)B_ * D_ * 2;          // 3.1 MB
  const size_t HBB  = (size_t)B_ * D_ * 2;          // 3.1 MB
  const size_t W1TB = (size_t)D_ * D_ * 2;          // 1.2 MB
  const size_t W2TB = (size_t)NPAD * D_ * 2;        // 172 KB
  const size_t CIDB = (size_t)B_ * S_ * 4;          // 2.1 MB

  char* p = (char*)d_ws;
  unsigned short* bowb = (unsigned short*)p;
  unsigned short* hb   = (unsigned short*)(p + BOWB);
  unsigned short* w1t  = (unsigned short*)(p + BOWB + HBB);
  unsigned short* w2t  = (unsigned short*)(p + BOWB + HBB + W1TB);
  int* cids            = (int*)(p + BOWB + HBB + W1TB + W2TB);
  int* cnts            = (int*)(p + BOWB + HBB + W1TB + W2TB + CIDB);

  prep_kernel<<<1184, 256, 0, stream>>>(ids, mask, W1, W2, cids, cnts, w1t, w2t);
  // 3 serialized passes: one L2-resident table slice per XCD per pass
  pool_sliced<<<2048, 256, 0, stream>>>(cids, cnts, table, bowb, 0);
  pool_sliced<<<2048, 256, 0, stream>>>(cids, cnts, table, bowb, 1);
  pool_sliced<<<2048, 256, 0, stream>>>(cids, cnts, table, bowb, 2);
  gemm1_mfma<<<dim3(B_ / G1_BM, D_ / G1_BN), 256, 0, stream>>>(bowb, w1t, b1, hb);
  gemm2_mfma<<<dim3(B_ / 16, NPAD / 16), 64, 0, stream>>>(hb, w2t, b2, out);
}

// Round 13
// 80.116 us; speedup vs baseline: 1.2363x; 1.2363x over previous
//
#include <hip/hip_runtime.h>

#define B_ 2048
#define S_ 256
#define V_ 30522
#define D_ 768
#define C_ 100
#define NPAD 112  // C_ padded to 7x16 for MFMA col tiles

// ---- bf16 helpers ---------------------------------------------------------
__device__ __forceinline__ unsigned short f2bf(float x) {
  unsigned u = __builtin_bit_cast(unsigned, x);
  u = (u + 0x7fffu + ((u >> 16) & 1u)) >> 16;
  return (unsigned short)u;
}
__device__ __forceinline__ float bf_lo(unsigned u) {
  return __builtin_bit_cast(float, u << 16);
}
__device__ __forceinline__ float bf_hi(unsigned u) {
  return __builtin_bit_cast(float, u & 0xffff0000u);
}

typedef __attribute__((ext_vector_type(8))) short bf16x8;
typedef __attribute__((ext_vector_type(4))) float f32x4;

// ---------------------------------------------------------------------------
// Fused prep:
//   [0,2048)        : table f32 -> bf16 (grid-stride float4->ushort4)
//   [2048,2560)     : compact ids (4 samples/block, 1 wave each)
//   [2560,3136)     : W1 [768][768] -> W1T bf16
//   [3136,3232)     : W2 [768][100] -> W2T [112][768] bf16 zero-padded
// ---------------------------------------------------------------------------
__global__ __launch_bounds__(256) void prep_kernel(
    const int* __restrict__ ids, const int* __restrict__ mask,
    const float* __restrict__ table, const float* __restrict__ w1,
    const float* __restrict__ w2, unsigned short* __restrict__ tbb,
    int* __restrict__ cids, int* __restrict__ cnts,
    unsigned short* __restrict__ w1t, unsigned short* __restrict__ w2t) {
  const int bid = blockIdx.x;
  const int t = threadIdx.x;
  if (bid < 2048) {
    const int n4 = (V_ * D_) / 4;
    int i = bid * 256 + t;
    const int stride = 2048 * 256;
    for (; i < n4; i += stride) {
      const float4 v = reinterpret_cast<const float4*>(table)[i];
      ushort4 o;
      o.x = f2bf(v.x); o.y = f2bf(v.y); o.z = f2bf(v.z); o.w = f2bf(v.w);
      reinterpret_cast<ushort4*>(tbb)[i] = o;
    }
  } else if (bid < 2560) {
    const int wv = t >> 6, lane = t & 63;
    const int b = (bid - 2048) * 4 + wv;
    const int base = b * S_;
    int total = 0;
#pragma unroll
    for (int r = 0; r < S_ / 64; ++r) {
      const int s = r * 64 + lane;
      const int m = mask[base + s];
      const unsigned long long bal = __ballot(m != 0);
      const int pre = __popcll(bal & ((1ull << lane) - 1ull));
      if (m) cids[base + total + pre] = ids[base + s];
      total += __popcll(bal);
    }
    if (lane == 0) cnts[b] = total;
  } else if (bid < 3136) {
    __shared__ float tile[32][33];
    const int local = bid - 2560;
    const int k0 = (local % 24) * 32, n0 = (local / 24) * 32;
    const int tx = t & 31, ty = t >> 5;
#pragma unroll
    for (int i = 0; i < 4; ++i)
      tile[ty + i * 8][tx] = w1[(size_t)(k0 + ty + i * 8) * D_ + n0 + tx];
    __syncthreads();
#pragma unroll
    for (int i = 0; i < 4; ++i) {
      const int n = ty + i * 8;
      w1t[(size_t)(n0 + n) * D_ + k0 + tx] = f2bf(tile[tx][n]);
    }
  } else {
    __shared__ float tile[32][33];
    const int local = bid - 3136;
    const int k0 = (local % 24) * 32, n0 = (local / 24) * 32;
    const int tx = t & 31, ty = t >> 5;
#pragma unroll
    for (int i = 0; i < 4; ++i) {
      const int k = k0 + ty + i * 8, n = n0 + tx;
      tile[ty + i * 8][tx] = (n < C_) ? w2[(size_t)k * C_ + n] : 0.f;
    }
    __syncthreads();
#pragma unroll
    for (int i = 0; i < 4; ++i) {
      const int n = n0 + ty + i * 8;
      if (n < NPAD)
        w2t[(size_t)n * D_ + k0 + tx] = f2bf(tile[tx][ty + i * 8]);
    }
  }
}

// ---------------------------------------------------------------------------
// Pool v9 (bf16 table, XCD-pinned 64-col chunks = 128B/row, 12 chunks):
//   pass 0: chunk = bid&7 (0..7), all 2048 samples, 8 samples/block.
//   pass 1: chunk = 8 + ((bid&7)>>1) (8..11) on an XCD PAIR; sample half
//           (bid&1): 1024 samples per XCD, 4 samples/block.
// Slice = 30522 x 128B = 3.9 MB, L2-resident per XCD. lane = 8 token-slots
// x 8 col-groups (16B int4 per lane = 8 bf16). 8 loads in flight.
// ---------------------------------------------------------------------------
__global__ __launch_bounds__(256) void pool_bf16_sliced(
    const int* __restrict__ cids, const int* __restrict__ cnts,
    const unsigned short* __restrict__ tbb, unsigned short* __restrict__ bowb,
    int pass) {
  __shared__ int sids[4][S_];
  const int bid = blockIdx.x;
  const int wv = threadIdx.x >> 6;
  const int lane = threadIdx.x & 63;
  const int sub = lane >> 3;       // token slot 0..7
  const int cg = lane & 7;         // col group (8 bf16)
  int chunk, smp0, nsmp;
  if (pass == 0) {
    chunk = bid & 7; smp0 = (bid >> 3) * 8; nsmp = 8;
  } else {
    const int x = bid & 7;
    chunk = 8 + (x >> 1);
    smp0 = (x & 1) * (B_ / 2) + (bid >> 3) * 4;
    nsmp = 4;
  }
  const int coff = chunk * 64 + cg * 8;  // bf16 column offset

  for (int s = wv; s < nsmp; s += 4) {
    const int smp = smp0 + s;
    const int cnt = cnts[smp];
    const int* cp = cids + (size_t)smp * S_;
    // stage ids to LDS (same-wave write->read, no barrier needed)
#pragma unroll
    for (int r = 0; r < S_ / 64; ++r) {
      const int idx = r * 64 + lane;
      sids[wv][idx] = (idx < cnt) ? cp[idx] : cp[0];
    }
    float a[8] = {};
    for (int base = 0; base < cnt; base += 64) {
      int4 v[8];
#pragma unroll
      for (int j = 0; j < 8; ++j) {
        int tt = base + j * 8 + sub;
        tt = tt < S_ ? tt : S_ - 1;
        const int id = sids[wv][tt];
        v[j] = *reinterpret_cast<const int4*>(tbb + (size_t)id * D_ + coff);
      }
#pragma unroll
      for (int j = 0; j < 8; ++j) {
        if (base + j * 8 + sub < cnt) {
          const unsigned* u = reinterpret_cast<const unsigned*>(&v[j]);
#pragma unroll
          for (int q = 0; q < 4; ++q) {
            a[2 * q]     += bf_lo(u[q]);
            a[2 * q + 1] += bf_hi(u[q]);
          }
        }
      }
    }
    // reduce over token slots (lane bits 3,4,5)
#pragma unroll
    for (int m = 8; m <= 32; m <<= 1) {
#pragma unroll
      for (int q = 0; q < 8; ++q) a[q] += __shfl_xor(a[q], m);
    }
    if (sub == 0) {
      const float inv = 1.0f / (float)cnt;
      unsigned short o[8];
#pragma unroll
      for (int q = 0; q < 8; ++q) o[q] = f2bf(a[q] * inv);
      *reinterpret_cast<int4*>(bowb + (size_t)smp * D_ + coff) =
          *reinterpret_cast<const int4*>(o);
    }
  }
}

// ---------------------------------------------------------------------------
// GEMM1 (MFMA bf16): Hb = relu(bow @ W1 + b1), bf16 out. BM=32 BN=64 BK=64.
// ---------------------------------------------------------------------------
#define G1_BM 32
#define G1_BN 64
#define G1_LDK 72  // 64 + 8 pad (ushorts) -> 144B row stride (16B aligned)

__global__ __launch_bounds__(256) void gemm1_mfma(
    const unsigned short* __restrict__ Ab, const unsigned short* __restrict__ Bt,
    const float* __restrict__ bias, unsigned short* __restrict__ Hb) {
  __shared__ unsigned short As[G1_BM][G1_LDK];
  __shared__ unsigned short Bs[G1_BN][G1_LDK];
  const int tid = threadIdx.x;
  const int bm = blockIdx.x * G1_BM;
  const int bn = blockIdx.y * G1_BN;
  const int w = tid >> 6;
  const int l = tid & 63;
  const int r = l & 15;
  const int g = l >> 4;

  f32x4 acc0 = {0.f, 0.f, 0.f, 0.f};
  f32x4 acc1 = {0.f, 0.f, 0.f, 0.f};

  const int ar = tid >> 3;          // 0..31
  const int kc8 = (tid & 7) * 8;    // 0,8,...,56

  for (int k0 = 0; k0 < D_; k0 += 64) {
    __syncthreads();
    *reinterpret_cast<int4*>(&As[ar][kc8]) =
        *reinterpret_cast<const int4*>(&Ab[(size_t)(bm + ar) * D_ + k0 + kc8]);
    *reinterpret_cast<int4*>(&Bs[ar][kc8]) =
        *reinterpret_cast<const int4*>(&Bt[(size_t)(bn + ar) * D_ + k0 + kc8]);
    *reinterpret_cast<int4*>(&Bs[ar + 32][kc8]) =
        *reinterpret_cast<const int4*>(&Bt[(size_t)(bn + ar + 32) * D_ + k0 + kc8]);
    __syncthreads();
    const bf16x8 a00 = *reinterpret_cast<const bf16x8*>(&As[r][g * 8]);
    const bf16x8 a01 = *reinterpret_cast<const bf16x8*>(&As[r][32 + g * 8]);
    const bf16x8 a10 = *reinterpret_cast<const bf16x8*>(&As[16 + r][g * 8]);
    const bf16x8 a11 = *reinterpret_cast<const bf16x8*>(&As[16 + r][32 + g * 8]);
    const bf16x8 b0 = *reinterpret_cast<const bf16x8*>(&Bs[w * 16 + r][g * 8]);
    const bf16x8 b1 = *reinterpret_cast<const bf16x8*>(&Bs[w * 16 + r][32 + g * 8]);
    acc0 = __builtin_amdgcn_mfma_f32_16x16x32_bf16(a00, b0, acc0, 0, 0, 0);
    acc0 = __builtin_amdgcn_mfma_f32_16x16x32_bf16(a01, b1, acc0, 0, 0, 0);
    acc1 = __builtin_amdgcn_mfma_f32_16x16x32_bf16(a10, b0, acc1, 0, 0, 0);
    acc1 = __builtin_amdgcn_mfma_f32_16x16x32_bf16(a11, b1, acc1, 0, 0, 0);
  }

  const int col = bn + w * 16 + r;
  const float bb = bias[col];
#pragma unroll
  for (int q = 0; q < 4; ++q) {
    const int row0 = bm + g * 4 + q;
    float v0 = acc0[q] + bb;
    v0 = v0 > 0.f ? v0 : 0.f;
    Hb[(size_t)row0 * D_ + col] = f2bf(v0);
    float v1 = acc1[q] + bb;
    v1 = v1 > 0.f ? v1 : 0.f;
    Hb[(size_t)(row0 + 16) * D_ + col] = f2bf(v1);
  }
}

// ---------------------------------------------------------------------------
// GEMM2 (MFMA bf16): scores = Hb @ W2 + b2, written twice (tuple return).
// ---------------------------------------------------------------------------
__global__ __launch_bounds__(64) void gemm2_mfma(
    const unsigned short* __restrict__ Hb, const unsigned short* __restrict__ w2t,
    const float* __restrict__ b2, float* __restrict__ out) {
  const int bm = blockIdx.x * 16;
  const int bn = blockIdx.y * 16;
  const int l = threadIdx.x;
  const int r = l & 15;
  const int g = l >> 4;

  const unsigned short* ap = Hb + (size_t)(bm + r) * D_ + g * 8;
  const unsigned short* bp = w2t + (size_t)(bn + r) * D_ + g * 8;

  f32x4 acc = {0.f, 0.f, 0.f, 0.f};
#pragma unroll
  for (int k0 = 0; k0 < D_; k0 += 32) {
    const bf16x8 av = *reinterpret_cast<const bf16x8*>(ap + k0);
    const bf16x8 bv = *reinterpret_cast<const bf16x8*>(bp + k0);
    acc = __builtin_amdgcn_mfma_f32_16x16x32_bf16(av, bv, acc, 0, 0, 0);
  }

  const int col = bn + r;
  if (col < C_) {
    const float bb = b2[col];
#pragma unroll
    for (int q = 0; q < 4; ++q) {
      const int row = bm + g * 4 + q;
      const float v = acc[q] + bb;
      out[(size_t)row * C_ + col] = v;
      out[(size_t)row * C_ + col + (size_t)B_ * C_] = v;
    }
  }
}

// ---------------------------------------------------------------------------
extern "C" void kernel_launch(void* const* d_in, const int* in_sizes, int n_in,
                              void* d_out, int out_size, void* d_ws,
                              size_t ws_size, hipStream_t stream) {
  const int* ids = (const int*)d_in[0];
  const int* mask = (const int*)d_in[1];
  const float* table = (const float*)d_in[2];
  const float* W1 = (const float*)d_in[3];
  const float* b1 = (const float*)d_in[4];
  const float* W2 = (const float*)d_in[5];
  const float* b2 = (const float*)d_in[6];
  float* out = (float*)d_out;

  const size_t BOWB = (size_t)B_ * D_ * 2;          // 3.1 MB
  const size_t HBB  = (size_t)B_ * D_ * 2;          // 3.1 MB
  const size_t W1TB = (size_t)D_ * D_ * 2;          // 1.2 MB
  const size_t W2TB = (size_t)NPAD * D_ * 2;        // 172 KB
  const size_t CIDB = (size_t)B_ * S_ * 4;          // 2.1 MB
  const size_t CNTB = (size_t)B_ * 4;               // 8 KB

  char* p = (char*)d_ws;
  unsigned short* bowb = (unsigned short*)p;
  unsigned short* hb   = (unsigned short*)(p + BOWB);
  unsigned short* w1t  = (unsigned short*)(p + BOWB + HBB);
  unsigned short* w2t  = (unsigned short*)(p + BOWB + HBB + W1TB);
  int* cids            = (int*)(p + BOWB + HBB + W1TB + W2TB);
  int* cnts            = (int*)(p + BOWB + HBB + W1TB + W2TB + CIDB);
  unsigned short* tbb  =
      (unsigned short*)(p + BOWB + HBB + W1TB + W2TB + CIDB + CNTB);

  prep_kernel<<<3232, 256, 0, stream>>>(ids, mask, table, W1, W2, tbb, cids,
                                        cnts, w1t, w2t);
  // pass 0: chunks 0-7 (one slice per XCD); pass 1: chunks 8-11 (XCD pairs)
  pool_bf16_sliced<<<2048, 256, 0, stream>>>(cids, cnts, tbb, bowb, 0);
  pool_bf16_sliced<<<2048, 256, 0, stream>>>(cids, cnts, tbb, bowb, 1);
  gemm1_mfma<<<dim3(B_ / G1_BM, D_ / G1_BN), 256, 0, stream>>>(bowb, w1t, b1, hb);
  gemm2_mfma<<<dim3(B_ / 16, NPAD / 16), 64, 0, stream>>>(hb, w2t, b2, out);
}